// Round 6
// baseline (272.138 us; speedup 1.0000x reference)
//
#include <hip/hip_runtime.h>
#include <hip/hip_bf16.h>
#include <cstdint>

// Problem constants
#define B_DIM 16384
#define DX 256
#define DH 512
#define DS 128
#define DT 128
#define KDIM 1024   // DX+DH+DS+DT
#define NDIM 2048   // 4*DH
#define HOUT 512

typedef __attribute__((ext_vector_type(8))) short short8;
typedef __attribute__((ext_vector_type(4))) float floatx4;

union bf16x8 {
  short8 v;
  __hip_bfloat16 b[8];
};

__device__ __forceinline__ float fast_sigmoid(float x) {
  return 1.f / (1.f + __expf(-x));
}
__device__ __forceinline__ float fast_tanh(float x) {
  float e = __expf(-2.f * x);
  return (1.f - e) / (1.f + e);
}

// ===========================================================================
// Chunk-flat packed operands, LINEAR k-quad order (no bank swizzle needed:
// the GEMM consumes fragments DIRECTLY from global -> VGPR, no LDS).
//   A tile (mb,kb) = 256 rows x 64 k = 32 chunks of 512 bf16 (1KB).
//     chunk t32 = s*16 + c (s = 32-k panel, c = 16-row group), lane i (0..63):
//     row = c*16 + i/4, kq = i&3; holds A[mb*256+row][kb*64+s*32+kq*8 ..+7]
//     flat = ((mb*16+kb)*32 + t32)*512 + i*8
//   A fragment (wave wm, frag mi, panel p) for lane (q,fr) =
//     Ap + mb*262144 + p*8192 + (wm*8+mi)*512 + (fr*4+q)*8   -- 16B/lane,
//     64 lanes cover the 1KB chunk exactly -> fully coalesced dwordx4.
// W tile (nblk,kb) = 128 packed cols x 64 k, 16 chunks; pcol = wn*64+g*16+hl
//   <-> orig col = g*512 + (nblk*32 + wn*16 + hl)  (g: 0=i,1=f,2=o,3=c~)
//   B fragment = Wp + nblk*131072 + p*4096 + (wn*4+ni)*512 + (fr*4+q)*8.
// ===========================================================================

__global__ __launch_bounds__(256) void pack_AW(
    const float* __restrict__ x, const float* __restrict__ h,
    const float* __restrict__ sp_, const float* __restrict__ tp_,
    const float* __restrict__ Wx, const float* __restrict__ Wh,
    const float* __restrict__ Ws, const float* __restrict__ Wt,
    __hip_bfloat16* __restrict__ Ap, __hip_bfloat16* __restrict__ Wp) {
  const int NA = B_DIM * KDIM / 8 / 256;   // 8192 A-blocks
  const int bid = blockIdx.x;
  if (bid < NA) {
    // ---- pack A: 256-row tiles, linear kq ----
    int tid = bid * 256 + threadIdx.x;     // 0 .. B_DIM*KDIM/8-1
    int i = tid & 63;
    int t32 = (tid >> 6) & 31;
    int tile = tid >> 11;                  // mb*16 + kb
    int kb = tile & 15, mb = tile >> 4;    // mb 0..63
    int s = t32 >> 4, c = t32 & 15;
    int row = c * 16 + (i >> 2);           // 0..255
    int kq = i & 3;
    int b = mb * 256 + row;
    int k = kb * 64 + s * 32 + kq * 8;
    const float* p;
    if (k < 768) {
      p = (k < 256) ? (x + (size_t)b * DX + k) : (h + (size_t)b * DH + (k - 256));
    } else {
      p = (k < 896) ? (sp_ + (size_t)b * DS + (k - 768))
                    : (tp_ + (size_t)b * DT + (k - 896));
    }
    floatx4 v0 = *(const floatx4*)p;
    floatx4 v1 = *(const floatx4*)(p + 4);
    bf16x8 o;
#pragma unroll
    for (int j = 0; j < 4; ++j) {
      o.b[j]     = __float2bfloat16(v0[j]);
      o.b[4 + j] = __float2bfloat16(v1[j]);
    }
    *(short8*)(Ap + (size_t)tid * 8) = o.v;
  } else {
    // ---- pack W: 128-col tiles, linear kq ----
    int tid = (bid - NA) * 256 + threadIdx.x;  // 0 .. NDIM*KDIM/8-1
    int i = tid & 63;
    int t16 = (tid >> 6) & 15;
    int tile = tid >> 10;                  // nblk*16 + kb
    int kb = tile & 15, nblk = tile >> 4;
    int s = t16 >> 3, c = t16 & 7;
    int pcol = c * 16 + (i >> 2);          // 0..127
    int kq = i & 3;
    int k = kb * 64 + s * 32 + kq * 8;
    int wn = pcol >> 6, g = (pcol >> 4) & 3, hl = pcol & 15;
    int col = g * 512 + nblk * 32 + wn * 16 + hl;
    const float* src; int kl;
    if (k < 256)      { src = Wx; kl = k; }
    else if (k < 768) { src = Wh; kl = k - 256; }
    else if (k < 896) { src = Ws; kl = k - 768; }
    else              { src = Wt; kl = k - 896; }
    bf16x8 o;
#pragma unroll
    for (int r = 0; r < 8; ++r)
      o.b[r] = __float2bfloat16(src[(size_t)(kl + r) * NDIM + col]);
    *(short8*)(Wp + (size_t)tid * 8) = o.v;
  }
}

// ---------------------------------------------------------------------------
// No-LDS (flatmm-style) GEMM: BM=256 x BN=128, 256 threads, 4 waves (2M x 2N),
// wave owns 128x64 = 8x4 acc. Fragments load global->VGPR directly (coalesced
// 1KB/instr from packed layout), ping/pong double-buffered at 32-k panel
// granularity. No LDS, no barriers, no staging: removes the ~45us/CU LDS-port
// serialization that capped rounds 0-5 at MfmaUtil ~30%.
// Per panel: 12 x global_load_dwordx4 (16B/lane) + 32 MFMA.
// L2 traffic ~1.5 GB total (~20-25 TB/s w/ XCD swizzle) - under 34.5 ceiling.
// ---------------------------------------------------------------------------
#define LOADP(Af, Bf, p) do {                                          \
    const __hip_bfloat16* ap_ = aT + (size_t)(p) * 8192;               \
    const __hip_bfloat16* bp_ = bT + (size_t)(p) * 4096;               \
    _Pragma("unroll")                                                  \
    for (int mi_ = 0; mi_ < 8; ++mi_)                                  \
      Af[mi_] = *(const short8*)(ap_ + mi_ * 512);                     \
    _Pragma("unroll")                                                  \
    for (int ni_ = 0; ni_ < 4; ++ni_)                                  \
      Bf[ni_] = *(const short8*)(bp_ + ni_ * 512);                     \
  } while (0)

#define MFMAP(Af, Bf) do {                                             \
    _Pragma("unroll")                                                  \
    for (int mi_ = 0; mi_ < 8; ++mi_)                                  \
      _Pragma("unroll")                                                \
      for (int ni_ = 0; ni_ < 4; ++ni_)                                \
        acc[mi_][ni_] = __builtin_amdgcn_mfma_f32_16x16x32_bf16(       \
            Af[mi_], Bf[ni_], acc[mi_][ni_], 0, 0, 0);                 \
  } while (0)

__global__ __launch_bounds__(256, 2) void lstm_gemm(
    const __hip_bfloat16* __restrict__ Ap, const __hip_bfloat16* __restrict__ Wp,
    const float* __restrict__ bh, const float* __restrict__ c_in,
    float* __restrict__ out) {
  const int tid = threadIdx.x;
  const int lane = tid & 63;
  const int wid = tid >> 6;      // 0..3
  const int wm = wid & 1;        // row half (128 rows of 256)
  const int wn = wid >> 1;       // col half (64 packed cols of 128)
  const int q = lane >> 4;
  const int fr = lane & 15;

  // XCD-aware bijective swizzle (1024 blocks, 1024%8==0)
  const int bid = blockIdx.x;
  const int wg = (bid & 7) * 128 + (bid >> 3);
  const int mb = wg >> 4;        // 0..63
  const int nblk = wg & 15;      // 0..15
  const int m0 = mb * 256;

  // Per-lane fragment bases (bf16 elements)
  const int ls = (fr * 4 + q) * 8;
  const __hip_bfloat16* aT =
      Ap + (size_t)mb * 262144 + (wm * 8) * 512 + ls;   // + p*8192 + mi*512
  const __hip_bfloat16* bT =
      Wp + (size_t)nblk * 131072 + (wn * 4) * 512 + ls; // + p*4096 + ni*512

  floatx4 acc[8][4];
#pragma unroll
  for (int i = 0; i < 8; ++i)
#pragma unroll
    for (int j = 0; j < 4; ++j) acc[i][j] = (floatx4)0.f;

  // Ping/pong panel buffers: 32 panels of 32-k.
  short8 aP[8], bP[4], aQ[8], bQ[4];
  LOADP(aP, bP, 0);
  for (int p = 0; p < 30; p += 2) {
    LOADP(aQ, bQ, p + 1);
    MFMAP(aP, bP);
    LOADP(aP, bP, p + 2);
    MFMAP(aQ, bQ);
  }
  LOADP(aQ, bQ, 31);
  MFMAP(aP, bP);
  MFMAP(aQ, bQ);

  // ---- In-register epilogue ----
  // acc[mi][g]: rows m0 + wm*128 + mi*16 + q*4 + r, gate g of hidden hh.
  const int hh = nblk * 32 + wn * 16 + fr;
  float bias[4];
#pragma unroll
  for (int g = 0; g < 4; ++g) bias[g] = bh[g * 512 + hh];

#pragma unroll
  for (int mi = 0; mi < 8; ++mi) {
#pragma unroll
    for (int r = 0; r < 4; ++r) {
      const size_t grow = (size_t)(m0 + wm * 128 + mi * 16 + q * 4 + r);
      const float pi = acc[mi][0][r] + bias[0];
      const float pf = acc[mi][1][r] + bias[1];
      const float po = acc[mi][2][r] + bias[2];
      const float pc = acc[mi][3][r] + bias[3];
      const float ig = fast_sigmoid(pi);
      const float fg = fast_sigmoid(pf);
      const float og = fast_sigmoid(po);
      const float cg = fast_tanh(pc);
      const float cc = fg * c_in[grow * HOUT + hh] + ig * cg;
      out[grow * HOUT + hh] = fast_tanh(og * cc);  // faithful: tanh(o*c_new)
      out[(size_t)B_DIM * HOUT + grow * HOUT + hh] = cc;
    }
  }
}

// ---------------------------------------------------------------------------
extern "C" void kernel_launch(void* const* d_in, const int* in_sizes, int n_in,
                              void* d_out, int out_size, void* d_ws, size_t ws_size,
                              hipStream_t stream) {
  const float* x  = (const float*)d_in[0];
  const float* h  = (const float*)d_in[1];
  const float* c  = (const float*)d_in[2];
  const float* sp = (const float*)d_in[3];
  const float* tp = (const float*)d_in[4];
  const float* Wx = (const float*)d_in[5];
  const float* Wh = (const float*)d_in[6];
  const float* bh = (const float*)d_in[7];
  const float* Ws = (const float*)d_in[8];
  const float* Wt = (const float*)d_in[9];
  float* out = (float*)d_out;

  __hip_bfloat16* Ap = (__hip_bfloat16*)d_ws;                                     // 32 MB
  __hip_bfloat16* Wp = (__hip_bfloat16*)((char*)d_ws + (size_t)B_DIM * KDIM * 2); // 4 MB

  const int nblk_A = B_DIM * KDIM / 8 / 256;   // 8192
  const int nblk_W = NDIM * KDIM / 8 / 256;    // 1024
  pack_AW<<<dim3(nblk_A + nblk_W), dim3(256), 0, stream>>>(
      x, h, sp, tp, Wx, Wh, Ws, Wt, Ap, Wp);
  lstm_gemm<<<dim3(1024), dim3(256), 0, stream>>>(Ap, Wp, bh, c, out);
}

// Round 7
// 231.610 us; speedup vs baseline: 1.1750x; 1.1750x over previous
//
#include <hip/hip_runtime.h>
#include <hip/hip_bf16.h>
#include <cstdint>

// Problem constants
#define B_DIM 16384
#define DX 256
#define DH 512
#define DS 128
#define DT 128
#define KDIM 1024   // DX+DH+DS+DT
#define NDIM 2048   // 4*DH
#define HOUT 512

#define NT 32       // K-tiles of BK=32
#define PAN 8192    // ushorts per 16KB panel slot (256 rows x 32 k x 2B)

typedef __attribute__((ext_vector_type(8))) short short8;
typedef __attribute__((ext_vector_type(4))) float floatx4;

union bf16x8 {
  short8 v;
  __hip_bfloat16 b[8];
};

__device__ __forceinline__ float fast_sigmoid(float x) {
  return 1.f / (1.f + __expf(-x));
}
__device__ __forceinline__ float fast_tanh(float x) {
  float e = __expf(-2.f * x);
  return (1.f - e) / (1.f + e);
}

// ===========================================================================
// Chunk-flat packed operands with BAKED-IN XOR bank swizzle (verified r4/r5:
// SQ_LDS_BANK_CONFLICT = 0).
//   A tile (mb,kb) = 256 rows x 64 k = 2 panels (s) x 16 row-groups (c) of
//   512-bf16 chunks. lane i: row = c*16 + i/4, kq_src = (i&3) ^ ((row>>1)&3);
//   holds A[mb*256+row][kb*64 + s*32 + kq_src*8 ..+7].
//   Panel (mb, t) [t = kb*2+s = 32-k index 0..31] = 16 KB CONTIGUOUS at
//   Ap + mb*262144 + t*8192.
// W tile (nb,kb) = 256 packed cols x 64 k, same chunk structure.
//   pcol = wn*64 + g*16 + hl  <->  orig col = g*512 + (nb*64 + wn*16 + hl)
//   (g: 0=i,1=f,2=o,3=c~) -> gate g = wave col-frag index -> register epilogue.
//   Panel (nb, t) = Wp + nb*262144/8... = nb*32768*8? -> nb*262144/... see code.
// ===========================================================================

__global__ __launch_bounds__(256) void pack_AW(
    const float* __restrict__ x, const float* __restrict__ h,
    const float* __restrict__ sp_, const float* __restrict__ tp_,
    const float* __restrict__ Wx, const float* __restrict__ Wh,
    const float* __restrict__ Ws, const float* __restrict__ Wt,
    __hip_bfloat16* __restrict__ Ap, __hip_bfloat16* __restrict__ Wp) {
  const int NA = B_DIM * KDIM / 8 / 256;   // 8192 A-blocks
  const int bid = blockIdx.x;
  if (bid < NA) {
    // ---- pack A: 256-row tiles, baked swizzle (verbatim r5) ----
    int tid = bid * 256 + threadIdx.x;     // 0 .. B_DIM*KDIM/8-1
    int i = tid & 63;
    int t32 = (tid >> 6) & 31;
    int tile = tid >> 11;                  // mb*16 + kb
    int kb = tile & 15, mb = tile >> 4;    // mb 0..63
    int s = t32 >> 4, c = t32 & 15;
    int row = c * 16 + (i >> 2);           // 0..255
    int kq = (i & 3) ^ ((row >> 1) & 3);   // baked swizzle
    int b = mb * 256 + row;
    int k = kb * 64 + s * 32 + kq * 8;
    const float* p;
    if (k < 768) {
      p = (k < 256) ? (x + (size_t)b * DX + k) : (h + (size_t)b * DH + (k - 256));
    } else {
      p = (k < 896) ? (sp_ + (size_t)b * DS + (k - 768))
                    : (tp_ + (size_t)b * DT + (k - 896));
    }
    floatx4 v0 = *(const floatx4*)p;
    floatx4 v1 = *(const floatx4*)(p + 4);
    bf16x8 o;
#pragma unroll
    for (int j = 0; j < 4; ++j) {
      o.b[j]     = __float2bfloat16(v0[j]);
      o.b[4 + j] = __float2bfloat16(v1[j]);
    }
    *(short8*)(Ap + (size_t)tid * 8) = o.v;
  } else {
    // ---- pack W: 256-pcol tiles, baked swizzle ----
    int tid = (bid - NA) * 256 + threadIdx.x;  // 0 .. NDIM*KDIM/8-1
    int i = tid & 63;
    int t32 = (tid >> 6) & 31;
    int tile = tid >> 11;                  // nb*16 + kb  (0..127)
    int kb = tile & 15, nb = tile >> 4;    // nb 0..7
    int s = t32 >> 4, c = t32 & 15;
    int pcol = c * 16 + (i >> 2);          // 0..255
    int kq = (i & 3) ^ ((pcol >> 1) & 3);  // baked swizzle
    int k = kb * 64 + s * 32 + kq * 8;
    int wn = pcol >> 6, g = (pcol >> 4) & 3, hl = pcol & 15;
    int col = g * 512 + nb * 64 + wn * 16 + hl;
    const float* src; int kl;
    if (k < 256)      { src = Wx; kl = k; }
    else if (k < 768) { src = Wh; kl = k - 256; }
    else if (k < 896) { src = Ws; kl = k - 768; }
    else              { src = Wt; kl = k - 896; }
    bf16x8 o;
#pragma unroll
    for (int r = 0; r < 8; ++r)
      o.b[r] = __float2bfloat16(src[(size_t)(kl + r) * NDIM + col]);
    *(short8*)(Wp + (size_t)tid * 8) = o.v;
  }
}

// ---------------------------------------------------------------------------
// Deep-ring GEMM: BM=BN=256, BK=32, 512 threads (8 waves, 2M x 4N), wave owns
// 128x64 = 8x4 acc. 3-slot LDS ring (3 x (16KB A + 16KB B) = 96 KB), stage
// lead = 2 K-tiles, ONE s_barrier per tile preceded by s_waitcnt vmcnt(4)
// (tile t+1 validated; tile t+2's 4 loads never drained). Issue-to-wait
// distance ~1.5 tiles (~500-600 cy of MFMA cover) vs r3's ~200 cy - that was
// r3's diagnosed failure. 2 setprio'd MFMA clusters of 16 per tile.
// ---------------------------------------------------------------------------
#define GLD(src, dst)                                              \
  __builtin_amdgcn_global_load_lds(                                \
      (const __attribute__((address_space(1))) void*)(src),        \
      (__attribute__((address_space(3))) void*)(dst), 16, 0, 0)

__global__ __launch_bounds__(512, 2) void lstm_gemm(
    const __hip_bfloat16* __restrict__ Ap, const __hip_bfloat16* __restrict__ Wp,
    const float* __restrict__ bh, const float* __restrict__ c_in,
    float* __restrict__ out) {
  extern __shared__ unsigned short smem[];   // 96 KB
  unsigned short* As = smem;                 // 3 slots x 8192
  unsigned short* Bs = smem + 3 * PAN;       // 3 slots x 8192

  const int tid = threadIdx.x;
  const int lane = tid & 63;
  const int wid = tid >> 6;      // 0..7
  const int wm = wid & 1;        // row half (128 rows of 256)
  const int wn = wid >> 1;       // col quarter (64 packed cols of 256)
  const int q = lane >> 4;
  const int fr = lane & 15;

  // XCD-aware bijective swizzle (512 blocks, 512%8==0)
  const int bid = blockIdx.x;
  const int wg = (bid & 7) * 64 + (bid >> 3);
  const int mb = wg >> 3;        // 0..63
  const int nb = wg & 7;         // 0..7
  const int m0 = mb * 256;

  // Fragment read offsets (ushort idx within a 16KB panel), XOR-swizzled.
  int aOff[8], bOff[4];
#pragma unroll
  for (int m = 0; m < 8; ++m) {
    int row = wm * 128 + m * 16 + fr;
    aOff[m] = row * 32 + (q ^ ((row >> 1) & 3)) * 8;
  }
#pragma unroll
  for (int n = 0; n < 4; ++n) {
    int prow = wn * 64 + n * 16 + fr;
    bOff[n] = prow * 32 + (q ^ ((prow >> 1) & 3)) * 8;
  }

  floatx4 acc[8][4];
#pragma unroll
  for (int i = 0; i < 8; ++i)
#pragma unroll
    for (int j = 0; j < 4; ++j) acc[i][j] = (floatx4)0.f;

  // Staging: panel t (16 KB) = 16 chunks of 1 KB; wave stages chunks
  // wid*2, wid*2+1. Per-lane global base (contiguous 16 B per lane).
  const int ch0 = wid * 2;
  const __hip_bfloat16* aStg = Ap + (size_t)mb * 262144 + ch0 * 512 + lane * 8;
  const __hip_bfloat16* bStg = Wp + (size_t)nb * 262144 + ch0 * 512 + lane * 8;
  const int dA = ch0 * 512;      // LDS dest base within slot (ushort idx)

  // ---- Prologue: stage T0 -> slot0, T1 -> slot1 (8 GLDs/thread) ----
  GLD(aStg,              &As[dA]);        GLD(aStg + 512,        &As[dA + 512]);
  GLD(bStg,              &Bs[dA]);        GLD(bStg + 512,        &Bs[dA + 512]);
  GLD(aStg + 8192,       &As[PAN + dA]);  GLD(aStg + 8192 + 512, &As[PAN + dA + 512]);
  GLD(bStg + 8192,       &Bs[PAN + dA]);  GLD(bStg + 8192 + 512, &Bs[PAN + dA + 512]);
  asm volatile("s_waitcnt vmcnt(4)\n\ts_barrier" ::: "memory");  // T0 landed

  int sR = 0;   // read slot (tile t)
  int sS = 2;   // stage slot (tile t+2)

  for (int t = 0; t < NT; ++t) {
    const unsigned short* Ar = As + sR * PAN;
    const unsigned short* Br = Bs + sR * PAN;
    const int ts = (t + 2 < NT) ? (t + 2) : (NT - 1);  // tail clamp (benign)
    const __hip_bfloat16* aP = aStg + (size_t)ts * PAN;
    const __hip_bfloat16* bP = bStg + (size_t)ts * PAN;
    unsigned short* Aw = As + sS * PAN;
    unsigned short* Bw = Bs + sS * PAN;

    // ---- phase 1: frags mi0-3 + all B; stage A(t+2) ----
    short8 a0[4], bf[4];
#pragma unroll
    for (int i = 0; i < 4; ++i) a0[i] = *(const short8*)(Ar + aOff[i]);
#pragma unroll
    for (int i = 0; i < 4; ++i) bf[i] = *(const short8*)(Br + bOff[i]);
    GLD(aP, &Aw[dA]);
    GLD(aP + 512, &Aw[dA + 512]);
    __builtin_amdgcn_s_setprio(1);
#pragma unroll
    for (int mi = 0; mi < 4; ++mi)
#pragma unroll
      for (int ni = 0; ni < 4; ++ni)
        acc[mi][ni] = __builtin_amdgcn_mfma_f32_16x16x32_bf16(
            a0[mi], bf[ni], acc[mi][ni], 0, 0, 0);
    __builtin_amdgcn_s_setprio(0);

    // ---- phase 2: frags mi4-7; stage B(t+2) ----
    short8 a1[4];
#pragma unroll
    for (int i = 0; i < 4; ++i) a1[i] = *(const short8*)(Ar + aOff[4 + i]);
    GLD(bP, &Bw[dA]);
    GLD(bP + 512, &Bw[dA + 512]);
    __builtin_amdgcn_s_setprio(1);
#pragma unroll
    for (int mi = 0; mi < 4; ++mi)
#pragma unroll
      for (int ni = 0; ni < 4; ++ni)
        acc[4 + mi][ni] = __builtin_amdgcn_mfma_f32_16x16x32_bf16(
            a1[mi], bf[ni], acc[4 + mi][ni], 0, 0, 0);
    __builtin_amdgcn_s_setprio(0);

    // Tile end: validate t+1 (its 4 loads landed), keep t+2's 4 in flight.
    asm volatile("s_waitcnt vmcnt(4)\n\ts_barrier" ::: "memory");

    sR = (sR == 2) ? 0 : sR + 1;
    sS = (sS == 2) ? 0 : sS + 1;
  }

  // ---- In-register epilogue ----
  // acc[mi][g]: rows m0 + wm*128 + mi*16 + q*4 + r, gate g of hidden hh.
  const int hh = nb * 64 + wn * 16 + fr;
  float bias[4];
#pragma unroll
  for (int g = 0; g < 4; ++g) bias[g] = bh[g * 512 + hh];

#pragma unroll
  for (int mi = 0; mi < 8; ++mi) {
#pragma unroll
    for (int r = 0; r < 4; ++r) {
      const size_t grow = (size_t)(m0 + wm * 128 + mi * 16 + q * 4 + r);
      const float pi = acc[mi][0][r] + bias[0];
      const float pf = acc[mi][1][r] + bias[1];
      const float po = acc[mi][2][r] + bias[2];
      const float pc = acc[mi][3][r] + bias[3];
      const float ig = fast_sigmoid(pi);
      const float fg = fast_sigmoid(pf);
      const float og = fast_sigmoid(po);
      const float cg = fast_tanh(pc);
      const float cc = fg * c_in[grow * HOUT + hh] + ig * cg;
      out[grow * HOUT + hh] = fast_tanh(og * cc);  // faithful: tanh(o*c_new)
      out[(size_t)B_DIM * HOUT + grow * HOUT + hh] = cc;
    }
  }
}

// ---------------------------------------------------------------------------
extern "C" void kernel_launch(void* const* d_in, const int* in_sizes, int n_in,
                              void* d_out, int out_size, void* d_ws, size_t ws_size,
                              hipStream_t stream) {
  const float* x  = (const float*)d_in[0];
  const float* h  = (const float*)d_in[1];
  const float* c  = (const float*)d_in[2];
  const float* sp = (const float*)d_in[3];
  const float* tp = (const float*)d_in[4];
  const float* Wx = (const float*)d_in[5];
  const float* Wh = (const float*)d_in[6];
  const float* bh = (const float*)d_in[7];
  const float* Ws = (const float*)d_in[8];
  const float* Wt = (const float*)d_in[9];
  float* out = (float*)d_out;

  __hip_bfloat16* Ap = (__hip_bfloat16*)d_ws;                                     // 32 MB
  __hip_bfloat16* Wp = (__hip_bfloat16*)((char*)d_ws + (size_t)B_DIM * KDIM * 2); // 4 MB

  static bool attr_done = false;
  if (!attr_done) {
    hipFuncSetAttribute((const void*)lstm_gemm,
                        hipFuncAttributeMaxDynamicSharedMemorySize, 98304);
    attr_done = true;
  }

  const int nblk_A = B_DIM * KDIM / 8 / 256;   // 8192
  const int nblk_W = NDIM * KDIM / 8 / 256;    // 1024
  pack_AW<<<dim3(nblk_A + nblk_W), dim3(256), 0, stream>>>(
      x, h, sp, tp, Wx, Wh, Ws, Wt, Ap, Wp);
  lstm_gemm<<<dim3(512), dim3(512), 98304, stream>>>(Ap, Wp, bh, c, out);
}